// Round 1
// 442.676 us; speedup vs baseline: 1.6541x; 1.6541x over previous
//
#include <hip/hip_runtime.h>
#include <hip/hip_bf16.h>

// Problem constants: B=4, T=2048, D=512, H=8, DK=64
#define T_SEQ 2048
#define N_TOK 4194304   // 4 * 2048 * 512 elements per [B,T,D] tensor

// Inputs: FLOAT32. Output: FLOAT32, (e2s, s2e) concat.
// ws (fused path, 48 MB): Q1,K1 [B,T,512] bf16; Vt1 [B,512,T] bf16; Q2,K2,Vt2.
// AO aliases Q per direction. Fallback (<48 MB ws): 24 MB, sequential.

typedef float f32x4  __attribute__((ext_vector_type(4)));
typedef short bf16x8 __attribute__((ext_vector_type(8)));

#define SCALE_Q 0.1875f   // 1.5 / sqrt(64)

__device__ __forceinline__ unsigned short f2b(float f) {
    __hip_bfloat16 h = __float2bfloat16(f);
    return *reinterpret_cast<unsigned short*>(&h);
}

__device__ __forceinline__ int pack2bf(float lo, float hi) {
    return ((int)f2b(hi) << 16) | (int)f2b(lo);
}

__device__ __forceinline__ bf16x8 ldg8(const unsigned short* p) {
    union { int4 i; bf16x8 b; } u;
    u.i = *reinterpret_cast<const int4*>(p);
    return u.b;
}

// async global->LDS DMA, 16B per lane; LDS dest = wave-uniform base + lane*16
typedef unsigned int u32_g __attribute__((address_space(1)));
typedef unsigned int u32_l __attribute__((address_space(3)));
__device__ __forceinline__ void gload_lds16(const void* g, void* l) {
    __builtin_amdgcn_global_load_lds((const u32_g*)g, (u32_l*)l, 16, 0, 0);
}

// ---------------------------------------------------------------------------
// Shared MFMA-GEMM tile machinery: 64x64 tile, BK=64, 256 threads (4 waves),
// wave w computes rows w*16..+15 x all 64 cols. LDS pitch 72 bf16.
// ---------------------------------------------------------------------------
#define MF_SETUP                                                               \
    __shared__ short Asm[64][72];                                              \
    __shared__ short Wsm[64][72];                                              \
    const int tid  = threadIdx.x;                                              \
    const int lane = tid & 63;                                                 \
    const int w4   = tid >> 6;                                                 \
    const int nl   = lane & 15;                                                \
    const int quad = lane >> 4;                                                \
    const int n0 = blockIdx.x * 64;                                            \
    const int m0 = blockIdx.y * 64;                                            \
    const int arow = tid >> 2;                                                 \
    const int acol = (tid & 3) * 16;                                           \
    f32x4 acc[4] = {};

#define MF_WRITE_W                                                             \
    {                                                                          \
        int4 x;                                                                \
        x.x = pack2bf(wv[0].x, wv[0].y); x.y = pack2bf(wv[0].z, wv[0].w);      \
        x.z = pack2bf(wv[1].x, wv[1].y); x.w = pack2bf(wv[1].z, wv[1].w);      \
        *reinterpret_cast<int4*>(&Wsm[arow][acol]) = x;                        \
        x.x = pack2bf(wv[2].x, wv[2].y); x.y = pack2bf(wv[2].z, wv[2].w);      \
        x.z = pack2bf(wv[3].x, wv[3].y); x.w = pack2bf(wv[3].z, wv[3].w);      \
        *reinterpret_cast<int4*>(&Wsm[arow][acol + 8]) = x;                    \
    }

#define MF_MMA_LOOP                                                            \
    _Pragma("unroll")                                                          \
    for (int kc = 0; kc < 2; ++kc) {                                           \
        const bf16x8 a = *reinterpret_cast<const bf16x8*>(                     \
            &Asm[w4 * 16 + nl][kc * 32 + quad * 8]);                           \
        _Pragma("unroll")                                                      \
        for (int c = 0; c < 4; ++c) {                                          \
            const bf16x8 bf = *reinterpret_cast<const bf16x8*>(                \
                &Wsm[c * 16 + nl][kc * 32 + quad * 8]);                        \
            acc[c] = __builtin_amdgcn_mfma_f32_16x16x32_bf16(a, bf, acc[c],    \
                                                             0, 0, 0);         \
        }                                                                      \
    }

// ---------------------------------------------------------------------------
// All six input projections in one dispatch. z = zbase + blockIdx.z:
//  0: Q1 = skel·Wq1 * SCALE   1: K1 = sens·Wk1   2: Vt1 = (sens·Wv1)^T
//  3: Q2 = sens·Wq2 * SCALE   4: K2 = skel·Wk2   5: Vt2 = (skel·Wv2)^T
// ---------------------------------------------------------------------------
__global__ __launch_bounds__(256)
void proj_all(const float* __restrict__ skel, const float* __restrict__ sens,
              const float* __restrict__ Wq1, const float* __restrict__ Wk1,
              const float* __restrict__ Wv1, const float* __restrict__ Wq2,
              const float* __restrict__ Wk2, const float* __restrict__ Wv2,
              unsigned short* __restrict__ Q1, unsigned short* __restrict__ K1,
              unsigned short* __restrict__ Vt1, unsigned short* __restrict__ Q2,
              unsigned short* __restrict__ K2, unsigned short* __restrict__ Vt2,
              int zbase)
{
    const int z = zbase + blockIdx.z;
    const float* A; const float* W; unsigned short* C;
    float alpha = 1.0f; bool trans = false;
    switch (z) {
        case 0:  A = skel; W = Wq1; C = Q1; alpha = SCALE_Q; break;
        case 1:  A = sens; W = Wk1; C = K1; break;
        case 2:  A = sens; W = Wv1; C = Vt1; trans = true; break;
        case 3:  A = sens; W = Wq2; C = Q2; alpha = SCALE_Q; break;
        case 4:  A = skel; W = Wk2; C = K2; break;
        default: A = skel; W = Wv2; C = Vt2; trans = true; break;
    }

    MF_SETUP
    const float* ap = A + (size_t)(m0 + arow) * 512 + acol;
    const float* wp = W + (size_t)(n0 + arow) * 512 + acol;
    float4 av[4], wv[4];
    #pragma unroll
    for (int j = 0; j < 4; ++j) {
        av[j] = *reinterpret_cast<const float4*>(ap + 4 * j);
        wv[j] = *reinterpret_cast<const float4*>(wp + 4 * j);
    }
    for (int it = 0; it < 8; ++it) {
        __syncthreads();
        {
            int4 x;
            x.x = pack2bf(av[0].x, av[0].y); x.y = pack2bf(av[0].z, av[0].w);
            x.z = pack2bf(av[1].x, av[1].y); x.w = pack2bf(av[1].z, av[1].w);
            *reinterpret_cast<int4*>(&Asm[arow][acol]) = x;
            x.x = pack2bf(av[2].x, av[2].y); x.y = pack2bf(av[2].z, av[2].w);
            x.z = pack2bf(av[3].x, av[3].y); x.w = pack2bf(av[3].z, av[3].w);
            *reinterpret_cast<int4*>(&Asm[arow][acol + 8]) = x;
        }
        MF_WRITE_W
        __syncthreads();
        if (it < 7) {
            const float* apn = ap + (it + 1) * 64;
            const float* wpn = wp + (it + 1) * 64;
            #pragma unroll
            for (int j = 0; j < 4; ++j) {
                av[j] = *reinterpret_cast<const float4*>(apn + 4 * j);
                wv[j] = *reinterpret_cast<const float4*>(wpn + 4 * j);
            }
        }
        MF_MMA_LOOP
    }

    if (!trans) {
        #pragma unroll
        for (int c = 0; c < 4; ++c)
            #pragma unroll
            for (int r = 0; r < 4; ++r)
                C[(size_t)(m0 + w4 * 16 + quad * 4 + r) * 512 + n0 + c * 16 + nl] =
                    f2b(acc[c][r] * alpha);
    } else {
        const int b  = m0 >> 11;
        const int t0 = (m0 & 2047) + w4 * 16 + quad * 4;
        #pragma unroll
        for (int c = 0; c < 4; ++c) {
            const int n = n0 + c * 16 + nl;
            ushort4 o;
            o.x = f2b(acc[c][0]);
            o.y = f2b(acc[c][1]);
            o.z = f2b(acc[c][2]);
            o.w = f2b(acc[c][3]);
            *reinterpret_cast<ushort4*>(C + (size_t)(b * 512 + n) * T_SEQ + t0) = o;
        }
    }
}

// ---------------------------------------------------------------------------
// Both output projections in one dispatch. z = zbase + blockIdx.z:
//  0: out1 = AO1·Wo1   1: out2 = AO2·Wo2      (A bf16, W fp32, C fp32)
// ---------------------------------------------------------------------------
__global__ __launch_bounds__(256)
void out_proj(const unsigned short* __restrict__ AO1, const float* __restrict__ Wo1,
              float* __restrict__ C1,
              const unsigned short* __restrict__ AO2, const float* __restrict__ Wo2,
              float* __restrict__ C2, int zbase)
{
    const int z = zbase + blockIdx.z;
    const unsigned short* A = z ? AO2 : AO1;
    const float* W = z ? Wo2 : Wo1;
    float* C = z ? C2 : C1;

    MF_SETUP
    const unsigned short* ap = A + (size_t)(m0 + arow) * 512 + acol;
    const float* wp = W + (size_t)(n0 + arow) * 512 + acol;
    int4 ai[2];
    float4 wv[4];
    ai[0] = *reinterpret_cast<const int4*>(ap);
    ai[1] = *reinterpret_cast<const int4*>(ap + 8);
    #pragma unroll
    for (int j = 0; j < 4; ++j)
        wv[j] = *reinterpret_cast<const float4*>(wp + 4 * j);
    for (int it = 0; it < 8; ++it) {
        __syncthreads();
        *reinterpret_cast<int4*>(&Asm[arow][acol])     = ai[0];
        *reinterpret_cast<int4*>(&Asm[arow][acol + 8]) = ai[1];
        MF_WRITE_W
        __syncthreads();
        if (it < 7) {
            const unsigned short* apn = ap + (it + 1) * 64;
            const float* wpn = wp + (it + 1) * 64;
            ai[0] = *reinterpret_cast<const int4*>(apn);
            ai[1] = *reinterpret_cast<const int4*>(apn + 8);
            #pragma unroll
            for (int j = 0; j < 4; ++j)
                wv[j] = *reinterpret_cast<const float4*>(wpn + 4 * j);
        }
        MF_MMA_LOOP
    }
    #pragma unroll
    for (int c = 0; c < 4; ++c)
        #pragma unroll
        for (int r = 0; r < 4; ++r)
            C[(size_t)(m0 + w4 * 16 + quad * 4 + r) * 512 + n0 + c * 16 + nl] =
                acc[c][r];
}

// ---------------------------------------------------------------------------
// MFMA flash attention, both directions in one dispatch (blockIdx.y >> 5).
// Block = 4 waves = one (dir,b,h,64-row q-tile); wave owns 16 q rows.
// K/V tiles staged into LDS via global_load_lds (double-buffered, issued at
// iteration top, drained vmcnt(0)+barrier at bottom -> structural prefetch,
// shared across the 4 waves). 16B-slot XOR swizzle (slot ^= row&7) applied as
// inverse swizzle on the GLOBAL source (gload_lds writes linearly) and the
// same XOR on the ds_read side -> 2-way bank aliasing only (free).
// S^T = K·Q^T (C-layout col=q), softmax via shfl_xor(16/32); P relayout via
// wave-private LDS; mask staged in LDS. AO aliases Q (block-local RAW only).
// ---------------------------------------------------------------------------
__global__ __launch_bounds__(256)
void attn_mfma(const unsigned short* Q1x, const unsigned short* __restrict__ K1x,
               const unsigned short* __restrict__ V1x, const int* __restrict__ m1x,
               unsigned short* AO1x,
               const unsigned short* Q2x, const unsigned short* __restrict__ K2x,
               const unsigned short* __restrict__ V2x, const int* __restrict__ m2x,
               unsigned short* AO2x)
{
    __shared__ short Kl[2][64][64];   // [buf][kv_row][d] (swizzled 16B slots)
    __shared__ short Vl[2][64][64];   // [buf][d_row][kv] (swizzled 16B slots)
    __shared__ short Pl[4][16][72];
    __shared__ int   mlds[T_SEQ];

    const int dir = blockIdx.y >> 5;
    const unsigned short* Q  = dir ? Q2x : Q1x;
    const unsigned short* K  = dir ? K2x : K1x;
    const unsigned short* Vt = dir ? V2x : V1x;
    const int* mask          = dir ? m2x : m1x;
    unsigned short* AO       = dir ? AO2x : AO1x;

    const int tid  = threadIdx.x;
    const int w    = tid >> 6;
    const int lane = tid & 63;
    const int nl   = lane & 15;
    const int quad = lane >> 4;
    const int qt = blockIdx.x;              // 0..31
    const int bh = blockIdx.y & 31;         // 0..31
    const int b = bh >> 3, h = bh & 7;
    const size_t tb = (size_t)b * (T_SEQ * 512);

    // staging geometry: each wave stages 16 K-rows + 16 V-rows per tile,
    // 2 issues of 1KB each (8 rows x 128B). Lane l -> row +(l>>3), slot l&7,
    // global chunk (l&7)^(l>>3)  (inverse of read-side slot^(row&7)).
    const int r8 = lane >> 3;
    const int cg = (lane & 7) ^ r8;

    // stage mask row for this batch
    {
        const int* mrow = mask + b * T_SEQ;
        *reinterpret_cast<int4*>(&mlds[tid * 8])     = *reinterpret_cast<const int4*>(&mrow[tid * 8]);
        *reinterpret_cast<int4*>(&mlds[tid * 8 + 4]) = *reinterpret_cast<const int4*>(&mrow[tid * 8 + 4]);
    }

    // Q B-frags (n=lane&15 => q row, k=quad*8+j)
    const unsigned short* qp = Q + tb + (size_t)(qt * 64 + w * 16 + nl) * 512 + h * 64 + quad * 8;
    const bf16x8 qb0 = ldg8(qp);
    const bf16x8 qb1 = ldg8(qp + 32);

    float m_run = -INFINITY, l_run = 0.0f;
    f32x4 o[4] = {};   // o[sd]: d = sd*16+nl (col), q = quad*4+reg (row)

    // prologue: stage tile 0 into buffer 0
    #pragma unroll
    for (int i = 0; i < 2; ++i) {
        const int r = w * 16 + i * 8;
        gload_lds16(K  + tb + (size_t)(r + r8) * 512 + h * 64 + cg * 8, &Kl[0][r][0]);
        gload_lds16(Vt + (size_t)(b * 512 + h * 64 + r + r8) * T_SEQ + cg * 8, &Vl[0][r][0]);
    }
    asm volatile("s_waitcnt vmcnt(0)" ::: "memory");
    __syncthreads();

    const int swz = nl & 7;

    for (int kt = 0; kt < 32; ++kt) {
        const int cur = kt & 1;
        short (*Kb)[64] = Kl[cur];
        short (*Vb)[64] = Vl[cur];

        // issue next tile's DMA (lands before next iteration's barrier)
        if (kt < 31) {
            short (*Kn)[64] = Kl[cur ^ 1];
            short (*Vn)[64] = Vl[cur ^ 1];
            #pragma unroll
            for (int i = 0; i < 2; ++i) {
                const int r = w * 16 + i * 8;
                gload_lds16(K  + tb + (size_t)((kt + 1) * 64 + r + r8) * 512 + h * 64 + cg * 8, &Kn[r][0]);
                gload_lds16(Vt + (size_t)(b * 512 + h * 64 + r + r8) * T_SEQ + (size_t)(kt + 1) * 64 + cg * 8, &Vn[r][0]);
            }
        }

        // scores S^T[kv][q]
        float p[4][4];
        float mx = -INFINITY;
        #pragma unroll
        for (int s = 0; s < 4; ++s) {
            const bf16x8 k0 = *reinterpret_cast<const bf16x8*>(&Kb[s * 16 + nl][(quad ^ swz) * 8]);
            const bf16x8 k1 = *reinterpret_cast<const bf16x8*>(&Kb[s * 16 + nl][((4 + quad) ^ swz) * 8]);
            f32x4 z = {};
            z = __builtin_amdgcn_mfma_f32_16x16x32_bf16(k0, qb0, z, 0, 0, 0);
            z = __builtin_amdgcn_mfma_f32_16x16x32_bf16(k1, qb1, z, 0, 0, 0);
            const int4 mm = *reinterpret_cast<const int4*>(&mlds[kt * 64 + s * 16 + quad * 4]);
            p[s][0] = (mm.x != 0) ? z[0] : -1e30f;
            p[s][1] = (mm.y != 0) ? z[1] : -1e30f;
            p[s][2] = (mm.z != 0) ? z[2] : -1e30f;
            p[s][3] = (mm.w != 0) ? z[3] : -1e30f;
            #pragma unroll
            for (int r = 0; r < 4; ++r) mx = fmaxf(mx, p[s][r]);
        }

        // online softmax over kv
        mx = fmaxf(mx, __shfl_xor(mx, 16));
        mx = fmaxf(mx, __shfl_xor(mx, 32));
        const float m_new = fmaxf(m_run, mx);
        const float al = __expf(m_run - m_new);
        float ps = 0.0f;
        #pragma unroll
        for (int s = 0; s < 4; ++s)
            #pragma unroll
            for (int r = 0; r < 4; ++r) {
                p[s][r] = __expf(p[s][r] - m_new);
                ps += p[s][r];
            }
        ps += __shfl_xor(ps, 16);
        ps += __shfl_xor(ps, 32);
        l_run = al * l_run + ps;
        m_run = m_new;

        // P: C-layout -> LDS [q][kv] (wave-private, wave-synchronous)
        #pragma unroll
        for (int s = 0; s < 4; ++s) {
            int2 pk;
            pk.x = pack2bf(p[s][0], p[s][1]);
            pk.y = pack2bf(p[s][2], p[s][3]);
            *reinterpret_cast<int2*>(&Pl[w][nl][s * 16 + quad * 4]) = pk;
        }

        // rescale O (alpha lives at lane q; O rows q=quad*4+r)
        const float a0 = __shfl(al, quad * 4 + 0);
        const float a1 = __shfl(al, quad * 4 + 1);
        const float a2 = __shfl(al, quad * 4 + 2);
        const float a3 = __shfl(al, quad * 4 + 3);
        #pragma unroll
        for (int sd = 0; sd < 4; ++sd) {
            o[sd][0] *= a0; o[sd][1] *= a1; o[sd][2] *= a2; o[sd][3] *= a3;
        }

        // P A-frags from LDS, O += P · V  (V frags read from LDS, swizzled)
        const bf16x8 pa0 = *reinterpret_cast<const bf16x8*>(&Pl[w][nl][quad * 8]);
        const bf16x8 pa1 = *reinterpret_cast<const bf16x8*>(&Pl[w][nl][32 + quad * 8]);
        #pragma unroll
        for (int sd = 0; sd < 4; ++sd) {
            const bf16x8 v0 = *reinterpret_cast<const bf16x8*>(&Vb[sd * 16 + nl][(quad ^ swz) * 8]);
            const bf16x8 v1 = *reinterpret_cast<const bf16x8*>(&Vb[sd * 16 + nl][((4 + quad) ^ swz) * 8]);
            o[sd] = __builtin_amdgcn_mfma_f32_16x16x32_bf16(pa0, v0, o[sd], 0, 0, 0);
            o[sd] = __builtin_amdgcn_mfma_f32_16x16x32_bf16(pa1, v1, o[sd], 0, 0, 0);
        }

        // drain this iteration's DMA, release buffers
        asm volatile("s_waitcnt vmcnt(0)" ::: "memory");
        __syncthreads();
    }

    // epilogue: AO[q][d] = O/l, bf16
    const float i0 = 1.0f / __shfl(l_run, quad * 4 + 0);
    const float i1 = 1.0f / __shfl(l_run, quad * 4 + 1);
    const float i2 = 1.0f / __shfl(l_run, quad * 4 + 2);
    const float i3 = 1.0f / __shfl(l_run, quad * 4 + 3);
    unsigned short* ob = AO + tb + (size_t)(qt * 64 + w * 16 + quad * 4) * 512 + h * 64 + nl;
    #pragma unroll
    for (int sd = 0; sd < 4; ++sd) {
        ob[0 * 512 + sd * 16] = f2b(o[sd][0] * i0);
        ob[1 * 512 + sd * 16] = f2b(o[sd][1] * i1);
        ob[2 * 512 + sd * 16] = f2b(o[sd][2] * i2);
        ob[3 * 512 + sd * 16] = f2b(o[sd][3] * i3);
    }
}

extern "C" void kernel_launch(void* const* d_in, const int* in_sizes, int n_in,
                              void* d_out, int out_size, void* d_ws, size_t ws_size,
                              hipStream_t stream) {
    const float* skel = (const float*)d_in[0];
    const float* sens = (const float*)d_in[1];
    const int* mask_skel = (const int*)d_in[2];
    const int* mask_sens = (const int*)d_in[3];
    const float* Wq_s2e = (const float*)d_in[4];
    const float* Wk_e   = (const float*)d_in[5];
    const float* Wv_e   = (const float*)d_in[6];
    const float* Wq_e2s = (const float*)d_in[7];
    const float* Wk_s   = (const float*)d_in[8];
    const float* Wv_s   = (const float*)d_in[9];
    const float* Wo_s   = (const float*)d_in[10];
    const float* Wo_e   = (const float*)d_in[11];
    float* out = (float*)d_out;   // fp32: [e2s (4M)][s2e (4M)]

    unsigned short* Q1 = (unsigned short*)d_ws;    // dir0 Q / AO (aliased)
    unsigned short* K1 = Q1 + N_TOK;
    unsigned short* V1 = K1 + N_TOK;               // Vt

    const bool big = ws_size >= (size_t)6 * N_TOK * sizeof(unsigned short);

    if (big) {
        unsigned short* Q2 = V1 + N_TOK;
        unsigned short* K2 = Q2 + N_TOK;
        unsigned short* V2 = K2 + N_TOK;
        // dir0 = s2e (out slot 1), dir1 = e2s (out slot 0)
        proj_all<<<dim3(8, 128, 6), 256, 0, stream>>>(
            skel, sens, Wq_s2e, Wk_e, Wv_e, Wq_e2s, Wk_s, Wv_s,
            Q1, K1, V1, Q2, K2, V2, 0);
        attn_mfma<<<dim3(32, 64), 256, 0, stream>>>(
            Q1, K1, V1, mask_sens, Q1,
            Q2, K2, V2, mask_skel, Q2);
        out_proj<<<dim3(8, 128, 2), 256, 0, stream>>>(
            Q1, Wo_e, out + N_TOK, Q2, Wo_s, out, 0);
    } else {
        // sequential fallback: reuse the 3-buffer workspace per direction
        proj_all<<<dim3(8, 128, 3), 256, 0, stream>>>(
            skel, sens, Wq_s2e, Wk_e, Wv_e, Wq_e2s, Wk_s, Wv_s,
            Q1, K1, V1, Q1, K1, V1, 0);
        attn_mfma<<<dim3(32, 32), 256, 0, stream>>>(
            Q1, K1, V1, mask_sens, Q1, Q1, K1, V1, mask_sens, Q1);
        out_proj<<<dim3(8, 128, 1), 256, 0, stream>>>(
            Q1, Wo_e, out + N_TOK, Q1, Wo_s, out, 0);
        proj_all<<<dim3(8, 128, 3), 256, 0, stream>>>(
            skel, sens, Wq_s2e, Wk_e, Wv_e, Wq_e2s, Wk_s, Wv_s,
            Q1, K1, V1, Q1, K1, V1, 3);
        attn_mfma<<<dim3(32, 32), 256, 0, stream>>>(
            Q1, K1, V1, mask_skel, Q1, Q1, K1, V1, mask_skel, Q1);
        out_proj<<<dim3(8, 128, 1), 256, 0, stream>>>(
            Q1, Wo_s, out, Q1, Wo_s, out, 1);
    }
}